// Round 4
// baseline (5773.534 us; speedup 1.0000x reference)
//
#include <hip/hip_runtime.h>
#include <math.h>

// Problem constants
constexpr int Bc = 64, Tc = 512, Hc = 512, HEADSc = 4, Lc = 16, Rc = 256, Ac = 9;
constexpr int DH = 128; // head dim

#define F_BIAS 1
#define F_PE   2
#define F_ADDC 4
#define F_RELU 8
#define F_DIV  16

// ---------------------------------------------------------------------------
// Generic tiled SGEMM, 64x64 tile, BK=16, 256 threads, 4x4 per thread.
// C[m,n] = sum_k A[m,k] * (BT ? B[n,k] : B[k,n])  (+ epilogue per flags)
// Batched via blockIdx.z decomposed as z1 = z>>2, z2 = z&3 with strides.
// ---------------------------------------------------------------------------
template<bool BT>
__global__ __launch_bounds__(256)
void sgemm_kernel(const float* __restrict__ A, const float* __restrict__ B,
                  float* __restrict__ C,
                  const float* __restrict__ bias, const float* __restrict__ pe,
                  int M, int N, int K, int lda, int ldb, int ldc,
                  long long s1A, long long s2A,
                  long long s1B, long long s2B,
                  long long s1C, long long s2C,
                  float divv, int flags)
{
    int z = blockIdx.z;
    int z1 = z >> 2, z2 = z & 3;
    A += (size_t)z1 * s1A + (size_t)z2 * s2A;
    B += (size_t)z1 * s1B + (size_t)z2 * s2B;
    C += (size_t)z1 * s1C + (size_t)z2 * s2C;

    __shared__ float As[16][68];
    __shared__ float Bs[16][68];

    int bm = blockIdx.y * 64, bn = blockIdx.x * 64;
    int tid = threadIdx.x;
    int tx = tid & 15, ty = tid >> 4;

    float acc[4][4] = {};

    for (int k0 = 0; k0 < K; k0 += 16) {
        #pragma unroll
        for (int j = 0; j < 4; j++) {
            int i = tid + 256 * j;
            int mm = i >> 4, kk = i & 15;
            int gm = bm + mm, gk = k0 + kk;
            float v = 0.f;
            if (gm < M && gk < K) v = A[(size_t)gm * lda + gk];
            As[kk][mm] = v;
        }
        #pragma unroll
        for (int j = 0; j < 4; j++) {
            int i = tid + 256 * j;
            float v = 0.f;
            if (!BT) {
                int kk = i >> 6, nn = i & 63;
                int gk = k0 + kk, gn = bn + nn;
                if (gk < K && gn < N) v = B[(size_t)gk * ldb + gn];
                Bs[kk][nn] = v;
            } else {
                int nn = i >> 4, kk = i & 15;
                int gk = k0 + kk, gn = bn + nn;
                if (gk < K && gn < N) v = B[(size_t)gn * ldb + gk];
                Bs[kk][nn] = v;
            }
        }
        __syncthreads();
        #pragma unroll
        for (int kk = 0; kk < 16; kk++) {
            float a0[4], b0[4];
            #pragma unroll
            for (int i = 0; i < 4; i++) a0[i] = As[kk][ty * 4 + i];
            #pragma unroll
            for (int j = 0; j < 4; j++) b0[j] = Bs[kk][tx * 4 + j];
            #pragma unroll
            for (int i = 0; i < 4; i++)
                #pragma unroll
                for (int j = 0; j < 4; j++)
                    acc[i][j] += a0[i] * b0[j];
        }
        __syncthreads();
    }

    #pragma unroll
    for (int i = 0; i < 4; i++) {
        int m = bm + ty * 4 + i;
        if (m >= M) continue;
        #pragma unroll
        for (int j = 0; j < 4; j++) {
            int n = bn + tx * 4 + j;
            if (n >= N) continue;
            float v = acc[i][j];
            if (flags & F_DIV)  v = v / divv;
            if (flags & F_BIAS) v += bias[n];
            if (flags & F_PE)   v += pe[(size_t)(m & (Tc - 1)) * Hc + n];
            if (flags & F_ADDC) v += C[(size_t)m * ldc + n];
            if (flags & F_RELU) v = fmaxf(v, 0.f);
            C[(size_t)m * ldc + n] = v;
        }
    }
}

// ---------------------------------------------------------------------------
// Positional encoding, double-precision (numpy promotes to float64 via the
// np.float64 scalar np.log(10000.0) under NEP-50), cast to float32.
// ---------------------------------------------------------------------------
__global__ void pe_kernel(float* __restrict__ pe)
{
    int idx = blockIdx.x * 256 + threadIdx.x;
    if (idx >= Tc * Hc) return;
    int t = idx >> 9, n = idx & (Hc - 1);
    int j = n >> 1;
    double div = exp(-log(10000.0) * (double)(2 * j) / (double)Hc);
    double arg = (double)t * div;
    pe[idx] = (float)((n & 1) ? cos(arg) : sin(arg));
}

// a[m,n] = dot(accl[m,:9], W[:,n]) + bias[n] + pe[t,n]   (m local to group)
__global__ __launch_bounds__(256)
void accl_kernel(const float* __restrict__ accl, const float* __restrict__ W,
                 const float* __restrict__ bias, const float* __restrict__ pe,
                 float* __restrict__ out)
{
    int idx = blockIdx.x * 256 + threadIdx.x;
    int n = idx & (Hc - 1);
    int m = idx >> 9;
    int t = m & (Tc - 1);
    const float* arow = accl + (size_t)m * Ac;
    float s = 0.f;
    #pragma unroll
    for (int i = 0; i < Ac; i++) s += arow[i] * W[i * Hc + n];
    s += bias[n];
    s += pe[t * Hc + n];
    out[idx] = s;
}

// x = dwconv(r, cr) + dwconv(a, ca), K=3, SAME, cross-correlation
__global__ __launch_bounds__(256)
void dwconv_kernel(const float* __restrict__ r, const float* __restrict__ a,
                   const float* __restrict__ cr, const float* __restrict__ ca,
                   float* __restrict__ x)
{
    int idx = blockIdx.x * 256 + threadIdx.x;
    int c = idx & (Hc - 1);
    int m = idx >> 9;
    int t = m & (Tc - 1);
    float vr = r[idx] * cr[Hc + c];
    if (t > 0)      vr = r[idx - Hc] * cr[c] + vr;
    if (t < Tc - 1) vr = vr + r[idx + Hc] * cr[2 * Hc + c];
    float va = a[idx] * ca[Hc + c];
    if (t > 0)      va = a[idx - Hc] * ca[c] + va;
    if (t < Tc - 1) va = va + a[idx + Hc] * ca[2 * Hc + c];
    x[idx] = vr + va;
}

// in-place row softmax over 512 columns, one block per row
__global__ __launch_bounds__(256)
void softmax_kernel(float* __restrict__ L)
{
    size_t base = (size_t)blockIdx.x * 512;
    int tid = threadIdx.x;
    float v0 = L[base + tid], v1 = L[base + tid + 256];
    __shared__ float buf[256];
    buf[tid] = fmaxf(v0, v1);
    __syncthreads();
    for (int s = 128; s > 0; s >>= 1) {
        if (tid < s) buf[tid] = fmaxf(buf[tid], buf[tid + s]);
        __syncthreads();
    }
    float mx = buf[0];
    __syncthreads();
    float e0 = expf(v0 - mx), e1 = expf(v1 - mx);
    buf[tid] = e0 + e1;
    __syncthreads();
    for (int s = 128; s > 0; s >>= 1) {
        if (tid < s) buf[tid] += buf[tid + s];
        __syncthreads();
    }
    float sum = buf[0];
    L[base + tid] = e0 / sum;
    L[base + tid + 256] = e1 / sum;
}

// out = LN(X + Y) * g + b, one block per row of 512 (out may alias X)
__global__ __launch_bounds__(256)
void add_ln_kernel(const float* __restrict__ X, const float* __restrict__ Y,
                   const float* __restrict__ g, const float* __restrict__ bta,
                   float* __restrict__ out)
{
    size_t base = (size_t)blockIdx.x * 512;
    int tid = threadIdx.x;
    float v0 = X[base + tid] + Y[base + tid];
    float v1 = X[base + tid + 256] + Y[base + tid + 256];
    __shared__ float buf[256];
    buf[tid] = v0 + v1;
    __syncthreads();
    for (int s = 128; s > 0; s >>= 1) {
        if (tid < s) buf[tid] += buf[tid + s];
        __syncthreads();
    }
    float mean = buf[0] / 512.f;
    __syncthreads();
    float d0 = v0 - mean, d1 = v1 - mean;
    buf[tid] = d0 * d0 + d1 * d1;
    __syncthreads();
    for (int s = 128; s > 0; s >>= 1) {
        if (tid < s) buf[tid] += buf[tid + s];
        __syncthreads();
    }
    float var = buf[0] / 512.f;
    float rs = 1.0f / sqrtf(var + 1e-5f);
    out[base + tid]       = d0 * rs * g[tid] + bta[tid];
    out[base + tid + 256] = d1 * rs * g[tid + 256] + bta[tid + 256];
}

// em[m, l] = dot(X[m,:512], W[:,l]) + bias[l], 16 rows per block
__global__ __launch_bounds__(256)
void em_kernel(const float* __restrict__ X, const float* __restrict__ W,
               const float* __restrict__ bias, float* __restrict__ out)
{
    __shared__ float xs[16][516];
    int r0 = blockIdx.x * 16;
    int tid = threadIdx.x;
    #pragma unroll 8
    for (int i = 0; i < 32; i++) {
        int idx = tid + 256 * i;
        int r = idx >> 9, c = idx & 511;
        xs[r][c] = X[(size_t)(r0 + r) * Hc + c];
    }
    __syncthreads();
    int r = tid >> 4, l = tid & 15;
    float s = 0.f;
    for (int k = 0; k < Hc; k++) s += xs[r][k] * W[k * Lc + l];
    s += bias[l];
    out[(size_t)(r0 + r) * Lc + l] = s;
}

// Viterbi: one block per batch, hist in LDS, exact numpy argmax semantics.
// d_out is read by the harness through its int32 branch (int64 reference is
// mapped to an int32 buffer) -> store integer tag values.
__global__ __launch_bounds__(64)
void viterbi_kernel(const float* __restrict__ em, const float* __restrict__ st,
                    const float* __restrict__ et, const float* __restrict__ trans,
                    int* __restrict__ out)
{
    int b = blockIdx.x;
    int tid = threadIdx.x;
    __shared__ float tr[Lc * Lc];
    __shared__ float sc[2][Lc];
    __shared__ unsigned char hist[Tc - 1][Lc];
    for (int i = tid; i < Lc * Lc; i += 64) tr[i] = trans[i];
    if (tid < Lc) sc[0][tid] = st[tid] + em[((size_t)b * Tc) * Lc + tid];
    __syncthreads();
    int cur = 0;
    for (int t = 1; t < Tc; t++) {
        if (tid < Lc) {
            float e = em[((size_t)b * Tc + t) * Lc + tid];
            float best = (sc[cur][0] + tr[tid]) + e;
            int bi = 0;
            #pragma unroll
            for (int i = 1; i < Lc; i++) {
                float v = (sc[cur][i] + tr[i * Lc + tid]) + e;
                if (v > best) { best = v; bi = i; }
            }
            sc[cur ^ 1][tid] = best;
            hist[t - 1][tid] = (unsigned char)bi;
        }
        __syncthreads();
        cur ^= 1;
    }
    if (tid == 0) {
        float best = sc[cur][0] + et[0];
        int tag = 0;
        #pragma unroll
        for (int j = 1; j < Lc; j++) {
            float v = sc[cur][j] + et[j];
            if (v > best) { best = v; tag = j; }
        }
        out[(size_t)b * Tc + (Tc - 1)] = tag;
        for (int t = Tc - 2; t >= 0; t--) {
            tag = hist[t][tag];
            out[(size_t)b * Tc + t] = tag;
        }
    }
}

// Diagnostic: if workspace is too small to run, signal its size via absmax.
__global__ void diag_kernel(int* __restrict__ out, int n, int val)
{
    int i = blockIdx.x * 256 + threadIdx.x;
    if (i < n) out[i] = val;
}

// ---------------------------------------------------------------------------
extern "C" void kernel_launch(void* const* d_in, const int* in_sizes, int n_in,
                              void* d_out, int out_size, void* d_ws, size_t ws_size,
                              hipStream_t stream)
{
    const float* rssi   = (const float*)d_in[0];
    const float* accl   = (const float*)d_in[1];
    const float* rssi_W = (const float*)d_in[2];
    const float* rssi_b = (const float*)d_in[3];
    const float* accl_W = (const float*)d_in[4];
    const float* accl_b = (const float*)d_in[5];
    const float* conv_r = (const float*)d_in[6];
    const float* conv_a = (const float*)d_in[7];
    const float* Wq     = (const float*)d_in[8];
    const float* Wk     = (const float*)d_in[9];
    const float* Wv     = (const float*)d_in[10];
    const float* Wo     = (const float*)d_in[11];
    const float* ln1_g  = (const float*)d_in[12];
    const float* ln1_b  = (const float*)d_in[13];
    const float* W1     = (const float*)d_in[14];
    const float* b1     = (const float*)d_in[15];
    const float* W2     = (const float*)d_in[16];
    const float* b2     = (const float*)d_in[17];
    const float* ln2_g  = (const float*)d_in[18];
    const float* ln2_b  = (const float*)d_in[19];
    const float* loc_W  = (const float*)d_in[20];
    const float* loc_b  = (const float*)d_in[21];
    const float* start_trans = (const float*)d_in[22];
    const float* end_trans   = (const float*)d_in[23];
    const float* trans       = (const float*)d_in[24];

    const int M = Bc * Tc;                       // 32768 rows
    const size_t S = (size_t)M * Hc;             // 16,777,216 floats / slab
    const size_t TH = (size_t)Tc * Hc;           // 262,144 floats
    const float sq = sqrtf((float)DH);
    dim3 blk(256);

    size_t total_f = ws_size / sizeof(float);
    // Floor: 2 slabs + 8 MiB scratch = ~142.6 MiB. If less, signal ws size.
    if (total_f < 2 * S + 8ull * Tc * Hc) {
        diag_kernel<<<dim3((out_size + 255) / 256), blk, 0, stream>>>(
            (int*)d_out, out_size, 1000000 + (int)(ws_size >> 20));
        return;
    }

    float* bufX = (float*)d_ws;      // x -> x1 -> x2 (in-place LNs)
    float* bufY = bufX + S;          // attn_out -> f
    float* scr  = bufY + S;          // phase-local scratch
    size_t scr_n = total_f - 2 * S;

    // Pick batch-group sizes / FFN chunk from available scratch.
    int Ge = 1;
    for (int g = 64; g >= 1; g >>= 1)
        if (TH + 2ull * g * TH <= scr_n) { Ge = g; break; }
    int Ga = 1;
    for (int g = 64; g >= 1; g >>= 1)
        if (8ull * g * TH <= scr_n) { Ga = g; break; }
    int Nc = 64;
    for (int n = 2048; n >= 64; n >>= 1)
        if ((size_t)M * n <= scr_n) { Nc = n; break; }

    // ---- 1. embed + conv, per batch-group Ge ----
    float* pe_buf = scr;
    float* rg = scr + TH;
    float* ag = rg + (size_t)Ge * TH;
    pe_kernel<<<dim3((Tc * Hc + 255) / 256), blk, 0, stream>>>(pe_buf);
    for (int g0 = 0; g0 < Bc; g0 += Ge) {
        int rows = Ge * Tc;
        sgemm_kernel<false><<<dim3(Hc / 64, rows / 64, 1), blk, 0, stream>>>(
            rssi + (size_t)g0 * Tc * Rc, rssi_W, rg, rssi_b, pe_buf,
            rows, Hc, Rc, Rc, Hc, Hc, 0, 0, 0, 0, 0, 0, 1.f, F_BIAS | F_PE);
        accl_kernel<<<dim3(rows * (Hc / 256)), blk, 0, stream>>>(
            accl + (size_t)g0 * Tc * Ac, accl_W, accl_b, pe_buf, ag);
        dwconv_kernel<<<dim3(rows * (Hc / 256)), blk, 0, stream>>>(
            rg, ag, conv_r, conv_a, bufX + (size_t)g0 * TH);
    }

    // ---- 2. attention, per batch-group Ga ----
    for (int g0 = 0; g0 < Bc; g0 += Ga) {
        int rows = Ga * Tc;
        const float* xg = bufX + (size_t)g0 * TH;
        float* qg = scr;
        float* kg = qg + (size_t)Ga * TH;
        float* vg = kg + (size_t)Ga * TH;
        float* og = vg + (size_t)Ga * TH;
        float* lg = og + (size_t)Ga * TH;   // Ga*HEADS*T*T floats (= Ga*4*TH)
        sgemm_kernel<false><<<dim3(Hc / 64, rows / 64, 1), blk, 0, stream>>>(
            xg, Wq, qg, nullptr, nullptr, rows, Hc, Hc, Hc, Hc, Hc,
            0, 0, 0, 0, 0, 0, 1.f, 0);
        sgemm_kernel<false><<<dim3(Hc / 64, rows / 64, 1), blk, 0, stream>>>(
            xg, Wk, kg, nullptr, nullptr, rows, Hc, Hc, Hc, Hc, Hc,
            0, 0, 0, 0, 0, 0, 1.f, 0);
        sgemm_kernel<false><<<dim3(Hc / 64, rows / 64, 1), blk, 0, stream>>>(
            xg, Wv, vg, nullptr, nullptr, rows, Hc, Hc, Hc, Hc, Hc,
            0, 0, 0, 0, 0, 0, 1.f, 0);
        // logits[b,h,q,k] = q.k / sqrt(dh)
        sgemm_kernel<true><<<dim3(Tc / 64, Tc / 64, Ga * HEADSc), blk, 0, stream>>>(
            qg, kg, lg, nullptr, nullptr,
            Tc, Tc, DH, Hc, Hc, Tc,
            (long long)TH, DH,
            (long long)TH, DH,
            (long long)HEADSc * Tc * Tc, (long long)Tc * Tc,
            sq, F_DIV);
        softmax_kernel<<<dim3(Ga * HEADSc * Tc), blk, 0, stream>>>(lg);
        // o = attn @ v
        sgemm_kernel<false><<<dim3(DH / 64, Tc / 64, Ga * HEADSc), blk, 0, stream>>>(
            lg, vg, og, nullptr, nullptr,
            Tc, DH, Tc, Tc, Hc, Hc,
            (long long)HEADSc * Tc * Tc, (long long)Tc * Tc,
            (long long)TH, DH,
            (long long)TH, DH,
            1.f, 0);
        // attn_out = o @ Wo
        sgemm_kernel<false><<<dim3(Hc / 64, rows / 64, 1), blk, 0, stream>>>(
            og, Wo, bufY + (size_t)g0 * TH, nullptr, nullptr,
            rows, Hc, Hc, Hc, Hc, Hc, 0, 0, 0, 0, 0, 0, 1.f, 0);
    }

    // ---- 3. x1 = LN(x + attn_out), in-place into bufX ----
    add_ln_kernel<<<dim3(M), blk, 0, stream>>>(bufX, bufY, ln1_g, ln1_b, bufX);

    // ---- 4. FFN, K-chunked by Nc columns of the hidden layer ----
    int nChunks = (4 * Hc) / Nc;
    for (int c = 0; c < nChunks; c++) {
        sgemm_kernel<false><<<dim3(Nc / 64, M / 64, 1), blk, 0, stream>>>(
            bufX, W1 + c * Nc, scr, b1 + c * Nc, nullptr,
            M, Nc, Hc, Hc, 4 * Hc, Nc, 0, 0, 0, 0, 0, 0, 1.f, F_BIAS | F_RELU);
        sgemm_kernel<false><<<dim3(Hc / 64, M / 64, 1), blk, 0, stream>>>(
            scr, W2 + (size_t)c * Nc * Hc, bufY, b2, nullptr,
            M, Hc, Nc, Nc, Hc, Hc, 0, 0, 0, 0, 0, 0, 1.f,
            (c == 0) ? F_BIAS : F_ADDC);
    }

    // ---- 5. x2 = LN(x1 + f), in-place into bufX ----
    add_ln_kernel<<<dim3(M), blk, 0, stream>>>(bufX, bufY, ln2_g, ln2_b, bufX);

    // ---- 6. emissions (M x 16) into scr ----
    em_kernel<<<dim3(M / 16), blk, 0, stream>>>(bufX, loc_W, loc_b, scr);

    // ---- 7. viterbi ----
    viterbi_kernel<<<dim3(Bc), dim3(64), 0, stream>>>(
        scr, start_trans, end_trans, trans, (int*)d_out);
}

// Round 6
// 4502.284 us; speedup vs baseline: 1.2824x; 1.2824x over previous
//
#include <hip/hip_runtime.h>
#include <math.h>

// Problem constants
constexpr int Bc = 64, Tc = 512, Hc = 512, HEADSc = 4, Lc = 16, Rc = 256, Ac = 9;
constexpr int DH = 128;

#define F_BIAS 1
#define F_PE   2
#define F_ADDC 4
#define F_RELU 8
#define F_DIV  16
#define F_QKV  32

using short8   = __attribute__((ext_vector_type(8)))  short;
using floatx16 = __attribute__((ext_vector_type(16))) float;
using ushort4v = __attribute__((ext_vector_type(4)))  unsigned short;

// Exact 3-way bf16 split by mantissa truncation: v == hi + mid + lo exactly
// (8+8+8 = 24 bits). No rounding anywhere -> emulated GEMM error comes only
// from the dropped lo*lo product (~2^-28 relative), i.e. fp32-class.
struct S3 { unsigned short h, m, l; };
__device__ inline S3 split3(float v)
{
    S3 r;
    unsigned u = __float_as_uint(v);
    r.h = (unsigned short)(u >> 16);
    float r1 = v - __uint_as_float(u & 0xffff0000u);
    unsigned u1 = __float_as_uint(r1);
    r.m = (unsigned short)(u1 >> 16);
    float r2 = r1 - __uint_as_float(u1 & 0xffff0000u);
    r.l = (unsigned short)(__float_as_uint(r2) >> 16);
    return r;
}

// ---------------------------------------------------------------------------
// MFMA bf16x8 GEMM. 128x128 tile, BK=32, 256 threads = 4 waves, each wave a
// 64x64 quadrant of 2x2 v_mfma_f32_32x32x16_bf16 tiles, 8 products per tile.
// A: fp32 [m][k] (split in-kernel). B: either fp32 [n][k] (split in-kernel)
// or pre-split bf16 planes Bsp[3][n][k] with plane stride bPS.
// M,N multiples of 128; K multiple of 32.
// ---------------------------------------------------------------------------
template<bool BSPLIT>
__global__ __launch_bounds__(256)
void mgemm(const float* __restrict__ A, const float* __restrict__ Bf,
           const unsigned short* __restrict__ Bsp, long long bPS,
           float* __restrict__ C, const float* __restrict__ bias,
           const float* __restrict__ pe,
           int M, int N, int K, int lda, int ldb, int ldc,
           long long s1A, long long s2A, long long s1B, long long s2B,
           long long s1C, long long s2C, float divv, int flags)
{
    int z = blockIdx.z, z1 = z >> 2, z2 = z & 3;
    A += (size_t)z1 * s1A + (size_t)z2 * s2A;
    if (!BSPLIT) Bf += (size_t)z1 * s1B + (size_t)z2 * s2B;
    C += (size_t)z1 * s1C + (size_t)z2 * s2C;

    __shared__ unsigned short Ah[128][40], Am[128][40], Al[128][40];
    __shared__ unsigned short Bh[128][40], Bm[128][40], Bl[128][40];

    int bm = blockIdx.y * 128, bn = blockIdx.x * 128;
    int tid = threadIdx.x;
    int lane = tid & 63, wave = tid >> 6;
    int wr = wave >> 1, wc = wave & 1;
    int l31 = lane & 31, khalf = lane >> 5;

    floatx16 acc[2][2];
    #pragma unroll
    for (int i = 0; i < 2; i++)
        #pragma unroll
        for (int j = 0; j < 2; j++)
            #pragma unroll
            for (int e = 0; e < 16; e++) acc[i][j][e] = 0.f;

    for (int k0 = 0; k0 < K; k0 += 32) {
        // ---- stage A (fp32 -> 3 bf16 planes) ----
        #pragma unroll
        for (int it = 0; it < 4; it++) {
            int s = tid + 256 * it;
            int mm = s >> 3, kc = (s & 7) << 2;
            float4 v = *(const float4*)(A + (size_t)(bm + mm) * lda + k0 + kc);
            ushort4v h, m, l;
            S3 s0 = split3(v.x); h[0] = s0.h; m[0] = s0.m; l[0] = s0.l;
            S3 s1 = split3(v.y); h[1] = s1.h; m[1] = s1.m; l[1] = s1.l;
            S3 s2 = split3(v.z); h[2] = s2.h; m[2] = s2.m; l[2] = s2.l;
            S3 s3 = split3(v.w); h[3] = s3.h; m[3] = s3.m; l[3] = s3.l;
            *(ushort4v*)&Ah[mm][kc] = h;
            *(ushort4v*)&Am[mm][kc] = m;
            *(ushort4v*)&Al[mm][kc] = l;
        }
        // ---- stage B ----
        if (BSPLIT) {
            #pragma unroll
            for (int it = 0; it < 2; it++) {
                int s = tid + 256 * it;
                int nn = s >> 2, kc = (s & 3) << 3;
                size_t go = (size_t)(bn + nn) * ldb + k0 + kc;
                *(short8*)&Bh[nn][kc] = *(const short8*)(Bsp + go);
                *(short8*)&Bm[nn][kc] = *(const short8*)(Bsp + bPS + go);
                *(short8*)&Bl[nn][kc] = *(const short8*)(Bsp + 2 * bPS + go);
            }
        } else {
            #pragma unroll
            for (int it = 0; it < 4; it++) {
                int s = tid + 256 * it;
                int nn = s >> 3, kc = (s & 7) << 2;
                float4 v = *(const float4*)(Bf + (size_t)(bn + nn) * ldb + k0 + kc);
                ushort4v h, m, l;
                S3 s0 = split3(v.x); h[0] = s0.h; m[0] = s0.m; l[0] = s0.l;
                S3 s1 = split3(v.y); h[1] = s1.h; m[1] = s1.m; l[1] = s1.l;
                S3 s2 = split3(v.z); h[2] = s2.h; m[2] = s2.m; l[2] = s2.l;
                S3 s3 = split3(v.w); h[3] = s3.h; m[3] = s3.m; l[3] = s3.l;
                *(ushort4v*)&Bh[nn][kc] = h;
                *(ushort4v*)&Bm[nn][kc] = m;
                *(ushort4v*)&Bl[nn][kc] = l;
            }
        }
        __syncthreads();

        #pragma unroll
        for (int s = 0; s < 2; s++) {
            int ko = s * 16 + khalf * 8;
            short8 a0[2], a1[2], a2[2], b0[2], b1[2], b2[2];
            #pragma unroll
            for (int i = 0; i < 2; i++) {
                int ar = wr * 64 + i * 32 + l31;
                a0[i] = *(const short8*)&Ah[ar][ko];
                a1[i] = *(const short8*)&Am[ar][ko];
                a2[i] = *(const short8*)&Al[ar][ko];
                int br = wc * 64 + i * 32 + l31;
                b0[i] = *(const short8*)&Bh[br][ko];
                b1[i] = *(const short8*)&Bm[br][ko];
                b2[i] = *(const short8*)&Bl[br][ko];
            }
            // 8 products: hh, hm, mh, hl, lh, mm, ml, lm  (drop ll ~ 2^-28)
            #pragma unroll
            for (int i = 0; i < 2; i++)
                #pragma unroll
                for (int j = 0; j < 2; j++)
                    acc[i][j] = __builtin_amdgcn_mfma_f32_32x32x16_bf16(a0[i], b0[j], acc[i][j], 0, 0, 0);
            #pragma unroll
            for (int i = 0; i < 2; i++)
                #pragma unroll
                for (int j = 0; j < 2; j++)
                    acc[i][j] = __builtin_amdgcn_mfma_f32_32x32x16_bf16(a0[i], b1[j], acc[i][j], 0, 0, 0);
            #pragma unroll
            for (int i = 0; i < 2; i++)
                #pragma unroll
                for (int j = 0; j < 2; j++)
                    acc[i][j] = __builtin_amdgcn_mfma_f32_32x32x16_bf16(a1[i], b0[j], acc[i][j], 0, 0, 0);
            #pragma unroll
            for (int i = 0; i < 2; i++)
                #pragma unroll
                for (int j = 0; j < 2; j++)
                    acc[i][j] = __builtin_amdgcn_mfma_f32_32x32x16_bf16(a0[i], b2[j], acc[i][j], 0, 0, 0);
            #pragma unroll
            for (int i = 0; i < 2; i++)
                #pragma unroll
                for (int j = 0; j < 2; j++)
                    acc[i][j] = __builtin_amdgcn_mfma_f32_32x32x16_bf16(a2[i], b0[j], acc[i][j], 0, 0, 0);
            #pragma unroll
            for (int i = 0; i < 2; i++)
                #pragma unroll
                for (int j = 0; j < 2; j++)
                    acc[i][j] = __builtin_amdgcn_mfma_f32_32x32x16_bf16(a1[i], b1[j], acc[i][j], 0, 0, 0);
            #pragma unroll
            for (int i = 0; i < 2; i++)
                #pragma unroll
                for (int j = 0; j < 2; j++)
                    acc[i][j] = __builtin_amdgcn_mfma_f32_32x32x16_bf16(a1[i], b2[j], acc[i][j], 0, 0, 0);
            #pragma unroll
            for (int i = 0; i < 2; i++)
                #pragma unroll
                for (int j = 0; j < 2; j++)
                    acc[i][j] = __builtin_amdgcn_mfma_f32_32x32x16_bf16(a2[i], b1[j], acc[i][j], 0, 0, 0);
        }
        __syncthreads();
    }

    // ---- epilogue: C/D layout col=lane&31, row=(reg&3)+8*(reg>>2)+4*(lane>>5)
    #pragma unroll
    for (int i = 0; i < 2; i++) {
        #pragma unroll
        for (int j = 0; j < 2; j++) {
            #pragma unroll
            for (int r = 0; r < 16; r++) {
                int m = bm + wr * 64 + i * 32 + (r & 3) + ((r >> 2) << 3) + (khalf << 2);
                int n = bn + wc * 64 + j * 32 + l31;
                float v = acc[i][j][r];
                if (flags & F_DIV)  v /= divv;
                if (flags & F_BIAS) v += bias[n];
                if (flags & F_PE)   v += pe[(size_t)(m & (Tc - 1)) * Hc + n];
                if (flags & F_QKV) {
                    long long gth = s1C;  // Ga*TH carried via s1C
                    if (n < 512) {
                        C[(size_t)m * 512 + n] = v;
                    } else if (n < 1024) {
                        C[gth + (size_t)m * 512 + (n - 512)] = v;
                    } else {
                        // V stored transposed: [b][h*128+d][t]
                        C[2 * gth + (size_t)(m >> 9) * (Tc * Hc)
                          + (size_t)(n - 1024) * Tc + (m & (Tc - 1))] = v;
                    }
                } else {
                    if (flags & F_ADDC) v += C[(size_t)m * ldc + n];
                    if (flags & F_RELU) v = fmaxf(v, 0.f);
                    C[(size_t)m * ldc + n] = v;
                }
            }
        }
    }
}

// ---------------------------------------------------------------------------
// Weight pre-split: W [K][N] fp32 -> out[3][N][K] bf16 planes (exact split).
// Grid (K/64, N/64), 256 threads, LDS transpose.
// ---------------------------------------------------------------------------
__global__ __launch_bounds__(256)
void wsplit_kernel(const float* __restrict__ W, unsigned short* __restrict__ out,
                   int K, int N, long long PS)
{
    __shared__ float t[64][65];
    int k0 = blockIdx.x * 64, n0 = blockIdx.y * 64;
    int tid = threadIdx.x;
    int c = tid & 63, r4 = tid >> 6;
    #pragma unroll
    for (int i = 0; i < 16; i++) {
        int r = r4 * 16 + i;
        t[r][c] = W[(size_t)(k0 + r) * N + n0 + c];
    }
    __syncthreads();
    #pragma unroll
    for (int i = 0; i < 16; i++) {
        int n = r4 * 16 + i;
        S3 s = split3(t[c][n]);
        size_t o = (size_t)(n0 + n) * K + k0 + c;
        out[o] = s.h; out[PS + o] = s.m; out[2 * PS + o] = s.l;
    }
}

// ---------------------------------------------------------------------------
// Positional encoding (float64 to match numpy promotion)
// ---------------------------------------------------------------------------
__global__ void pe_kernel(float* __restrict__ pe)
{
    int idx = blockIdx.x * 256 + threadIdx.x;
    if (idx >= Tc * Hc) return;
    int t = idx >> 9, n = idx & (Hc - 1);
    int j = n >> 1;
    double div = exp(-log(10000.0) * (double)(2 * j) / (double)Hc);
    double arg = (double)t * div;
    pe[idx] = (float)((n & 1) ? cos(arg) : sin(arg));
}

// a[m,n] = dot(accl[m,:9], W[:,n]) + bias[n] + pe[t,n]
__global__ __launch_bounds__(256)
void accl_kernel(const float* __restrict__ accl, const float* __restrict__ W,
                 const float* __restrict__ bias, const float* __restrict__ pe,
                 float* __restrict__ out)
{
    int idx = blockIdx.x * 256 + threadIdx.x;
    int n = idx & (Hc - 1);
    int m = idx >> 9;
    int t = m & (Tc - 1);
    const float* arow = accl + (size_t)m * Ac;
    float s = 0.f;
    #pragma unroll
    for (int i = 0; i < Ac; i++) s += arow[i] * W[i * Hc + n];
    s += bias[n];
    s += pe[t * Hc + n];
    out[idx] = s;
}

// x = dwconv(r, cr) + dwconv(a, ca), K=3, SAME
__global__ __launch_bounds__(256)
void dwconv_kernel(const float* __restrict__ r, const float* __restrict__ a,
                   const float* __restrict__ cr, const float* __restrict__ ca,
                   float* __restrict__ x)
{
    int idx = blockIdx.x * 256 + threadIdx.x;
    int c = idx & (Hc - 1);
    int m = idx >> 9;
    int t = m & (Tc - 1);
    float vr = r[idx] * cr[Hc + c];
    if (t > 0)      vr = r[idx - Hc] * cr[c] + vr;
    if (t < Tc - 1) vr = vr + r[idx + Hc] * cr[2 * Hc + c];
    float va = a[idx] * ca[Hc + c];
    if (t > 0)      va = a[idx - Hc] * ca[c] + va;
    if (t < Tc - 1) va = va + a[idx + Hc] * ca[2 * Hc + c];
    x[idx] = vr + va;
}

// in-place row softmax over 512 columns, one block per row
__global__ __launch_bounds__(256)
void softmax_kernel(float* __restrict__ L)
{
    size_t base = (size_t)blockIdx.x * 512;
    int tid = threadIdx.x;
    float v0 = L[base + tid], v1 = L[base + tid + 256];
    __shared__ float buf[256];
    buf[tid] = fmaxf(v0, v1);
    __syncthreads();
    for (int s = 128; s > 0; s >>= 1) {
        if (tid < s) buf[tid] = fmaxf(buf[tid], buf[tid + s]);
        __syncthreads();
    }
    float mx = buf[0];
    __syncthreads();
    float e0 = expf(v0 - mx), e1 = expf(v1 - mx);
    buf[tid] = e0 + e1;
    __syncthreads();
    for (int s = 128; s > 0; s >>= 1) {
        if (tid < s) buf[tid] += buf[tid + s];
        __syncthreads();
    }
    float sum = buf[0];
    L[base + tid] = e0 / sum;
    L[base + tid + 256] = e1 / sum;
}

// out = LN(X + Y) * g + b, one block per row of 512 (out may alias X)
__global__ __launch_bounds__(256)
void add_ln_kernel(const float* __restrict__ X, const float* __restrict__ Y,
                   const float* __restrict__ g, const float* __restrict__ bta,
                   float* __restrict__ out)
{
    size_t base = (size_t)blockIdx.x * 512;
    int tid = threadIdx.x;
    float v0 = X[base + tid] + Y[base + tid];
    float v1 = X[base + tid + 256] + Y[base + tid + 256];
    __shared__ float buf[256];
    buf[tid] = v0 + v1;
    __syncthreads();
    for (int s = 128; s > 0; s >>= 1) {
        if (tid < s) buf[tid] += buf[tid + s];
        __syncthreads();
    }
    float mean = buf[0] / 512.f;
    __syncthreads();
    float d0 = v0 - mean, d1 = v1 - mean;
    buf[tid] = d0 * d0 + d1 * d1;
    __syncthreads();
    for (int s = 128; s > 0; s >>= 1) {
        if (tid < s) buf[tid] += buf[tid + s];
        __syncthreads();
    }
    float var = buf[0] / 512.f;
    float rs = 1.0f / sqrtf(var + 1e-5f);
    out[base + tid]       = d0 * rs * g[tid] + bta[tid];
    out[base + tid + 256] = d1 * rs * g[tid + 256] + bta[tid + 256];
}

// em[m, l] = dot(X[m,:512], W[:,l]) + bias[l]; W cached in LDS
__global__ __launch_bounds__(256)
void em_kernel(const float* __restrict__ X, const float* __restrict__ W,
               const float* __restrict__ bias, float* __restrict__ out)
{
    __shared__ float Wl[8192];
    int tid = threadIdx.x;
    #pragma unroll
    for (int i = 0; i < 32; i++) Wl[tid + 256 * i] = W[tid + 256 * i];
    __syncthreads();
    int r = tid >> 4, l = tid & 15;
    const float* xr = X + ((size_t)blockIdx.x * 16 + r) * Hc;
    float s = 0.f;
    #pragma unroll 8
    for (int k = 0; k < Hc; k++) s += xr[k] * Wl[k * Lc + l];
    s += bias[l];
    out[((size_t)blockIdx.x * 16 + r) * Lc + l] = s;
}

// Viterbi with one-step em prefetch; int32 output
__global__ __launch_bounds__(64)
void viterbi_kernel(const float* __restrict__ em, const float* __restrict__ st,
                    const float* __restrict__ et, const float* __restrict__ trans,
                    int* __restrict__ out)
{
    int b = blockIdx.x;
    int tid = threadIdx.x;
    __shared__ float tr[Lc * Lc];
    __shared__ float sc[2][Lc];
    __shared__ unsigned char hist[Tc - 1][Lc];
    for (int i = tid; i < Lc * Lc; i += 64) tr[i] = trans[i];
    float e_next = 0.f;
    if (tid < Lc) {
        sc[0][tid] = st[tid] + em[(size_t)b * Tc * Lc + tid];
        e_next = em[(size_t)b * Tc * Lc + Lc + tid];
    }
    __syncthreads();
    int cur = 0;
    for (int t = 1; t < Tc; t++) {
        float e = e_next;
        if (tid < Lc && t + 1 < Tc)
            e_next = em[((size_t)b * Tc + t + 1) * Lc + tid];
        if (tid < Lc) {
            float best = (sc[cur][0] + tr[tid]) + e;
            int bi = 0;
            #pragma unroll
            for (int i = 1; i < Lc; i++) {
                float v = (sc[cur][i] + tr[i * Lc + tid]) + e;
                if (v > best) { best = v; bi = i; }
            }
            sc[cur ^ 1][tid] = best;
            hist[t - 1][tid] = (unsigned char)bi;
        }
        __syncthreads();
        cur ^= 1;
    }
    if (tid == 0) {
        float best = sc[cur][0] + et[0];
        int tag = 0;
        #pragma unroll
        for (int j = 1; j < Lc; j++) {
            float v = sc[cur][j] + et[j];
            if (v > best) { best = v; tag = j; }
        }
        out[(size_t)b * Tc + (Tc - 1)] = tag;
        for (int t = Tc - 2; t >= 0; t--) {
            tag = hist[t][tag];
            out[(size_t)b * Tc + t] = tag;
        }
    }
}

__global__ void diag_kernel(int* __restrict__ out, int n, int val)
{
    int i = blockIdx.x * 256 + threadIdx.x;
    if (i < n) out[i] = val;
}

// ---------------------------------------------------------------------------
extern "C" void kernel_launch(void* const* d_in, const int* in_sizes, int n_in,
                              void* d_out, int out_size, void* d_ws, size_t ws_size,
                              hipStream_t stream)
{
    const float* rssi   = (const float*)d_in[0];
    const float* accl   = (const float*)d_in[1];
    const float* rssi_W = (const float*)d_in[2];
    const float* rssi_b = (const float*)d_in[3];
    const float* accl_W = (const float*)d_in[4];
    const float* accl_b = (const float*)d_in[5];
    const float* conv_r = (const float*)d_in[6];
    const float* conv_a = (const float*)d_in[7];
    const float* Wq     = (const float*)d_in[8];
    const float* Wk     = (const float*)d_in[9];
    const float* Wv     = (const float*)d_in[10];
    const float* Wo     = (const float*)d_in[11];
    const float* ln1_g  = (const float*)d_in[12];
    const float* ln1_b  = (const float*)d_in[13];
    const float* W1     = (const float*)d_in[14];
    const float* b1     = (const float*)d_in[15];
    const float* W2     = (const float*)d_in[16];
    const float* b2     = (const float*)d_in[17];
    const float* ln2_g  = (const float*)d_in[18];
    const float* ln2_b  = (const float*)d_in[19];
    const float* loc_W  = (const float*)d_in[20];
    const float* loc_b  = (const float*)d_in[21];
    const float* start_trans = (const float*)d_in[22];
    const float* end_trans   = (const float*)d_in[23];
    const float* trans       = (const float*)d_in[24];

    const int M = Bc * Tc;                        // 32768
    const size_t S = (size_t)M * Hc;              // 16,777,216 floats
    const size_t TH = (size_t)Tc * Hc;            // 262,144
    const long long TT = (long long)Tc * Tc;      // 262,144
    const float sq = sqrtf((float)DH);
    dim3 blk(256);

    // scratch layout (floats): bufX | bufY | wbuf(4,915,200) | pe | work
    const size_t WBUF_SH = 9830400ull;            // shorts
    const size_t WBUF_F  = WBUF_SH / 2;
    size_t total_f = ws_size / sizeof(float);
    size_t work_min = (size_t)M * 128;            // Nc=128 FFN hidden chunk
    if (total_f < 2 * S + WBUF_F + TH + work_min) {
        diag_kernel<<<dim3((out_size + 255) / 256), blk, 0, stream>>>(
            (int*)d_out, out_size, 1000000 + (int)(ws_size >> 20));
        return;
    }

    float* bufX = (float*)d_ws;
    float* bufY = bufX + S;
    unsigned short* wbuf  = (unsigned short*)(bufY + S);
    unsigned short* rssiT = wbuf;                 // [3][512][256]
    unsigned short* qkvT  = wbuf + 393216;        // [3][1536][512]
    unsigned short* WoT   = wbuf + 2752512;       // [3][512][512]
    unsigned short* W1T   = wbuf + 3538944;       // [3][2048][512]
    unsigned short* W2T   = wbuf + 6684672;       // [3][512][2048]
    float* pe_buf = (float*)(wbuf + WBUF_SH);
    float* work = pe_buf + TH;
    size_t work_n = total_f - 2 * S - WBUF_F - TH;

    int Ge = 1;
    for (int g = 64; g >= 1; g >>= 1) if ((size_t)g * TH <= work_n) { Ge = g; break; }
    int Ga = 1;
    for (int g = 64; g >= 1; g >>= 1) if (8ull * g * TH <= work_n) { Ga = g; break; }
    int Nc = 128;
    for (int n = 2048; n >= 128; n >>= 1) if ((size_t)M * n <= work_n) { Nc = n; break; }

    // ---- 0. pe + weight pre-split ----
    pe_kernel<<<dim3((Tc * Hc + 255) / 256), blk, 0, stream>>>(pe_buf);
    wsplit_kernel<<<dim3(Rc / 64, Hc / 64), blk, 0, stream>>>(rssi_W, rssiT, Rc, Hc, 131072LL);
    wsplit_kernel<<<dim3(8, 8),  blk, 0, stream>>>(Wq, qkvT,          512, 512, 786432LL);
    wsplit_kernel<<<dim3(8, 8),  blk, 0, stream>>>(Wk, qkvT + 262144, 512, 512, 786432LL);
    wsplit_kernel<<<dim3(8, 8),  blk, 0, stream>>>(Wv, qkvT + 524288, 512, 512, 786432LL);
    wsplit_kernel<<<dim3(8, 8),  blk, 0, stream>>>(Wo, WoT, 512, 512, 262144LL);
    wsplit_kernel<<<dim3(8, 32), blk, 0, stream>>>(W1, W1T, 512, 2048, 1048576LL);
    wsplit_kernel<<<dim3(32, 8), blk, 0, stream>>>(W2, W2T, 2048, 512, 1048576LL);

    // ---- 1. embed: a -> bufY (full), r -> work (grouped), x -> bufX ----
    accl_kernel<<<dim3(M * (Hc / 256)), blk, 0, stream>>>(accl, accl_W, accl_b, pe_buf, bufY);
    for (int g0 = 0; g0 < Bc; g0 += Ge) {
        int rows = Ge * Tc;
        mgemm<true><<<dim3(Hc / 128, rows / 128, 1), blk, 0, stream>>>(
            rssi + (size_t)g0 * Tc * Rc, nullptr, rssiT, 131072LL,
            work, rssi_b, pe_buf,
            rows, Hc, Rc, Rc, Rc, Hc,
            0, 0, 0, 0, 0, 0, 1.f, F_BIAS | F_PE);
        dwconv_kernel<<<dim3(rows * (Hc / 256)), blk, 0, stream>>>(
            work, bufY + (size_t)g0 * TH, conv_r, conv_a, bufX + (size_t)g0 * TH);
    }

    // ---- 2. attention per batch-group Ga ----
    for (int g0 = 0; g0 < Bc; g0 += Ga) {
        int rows = Ga * Tc;
        long long gth = (long long)Ga * TH;
        float* qg = work;                 // [rows][512]
        float* kg = work + gth;           // [rows][512]
        float* vg = work + 2 * gth;       // vT: [b][h*128+d][t]
        float* og = work + 3 * gth;       // [rows][512]
        float* lg = work + 4 * gth;       // [Ga][HEADS][T][T]
        // fused QKV (V transposed) via F_QKV, gth carried in s1C
        mgemm<true><<<dim3(1536 / 128, rows / 128, 1), blk, 0, stream>>>(
            bufX + (size_t)g0 * TH, nullptr, qkvT, 786432LL,
            qg, nullptr, nullptr,
            rows, 1536, Hc, Hc, 512, 0,
            0, 0, 0, 0, gth, 0, 1.f, F_QKV);
        // logits = q.k^T / sqrt(dh)
        mgemm<false><<<dim3(Tc / 128, Tc / 128, Ga * HEADSc), blk, 0, stream>>>(
            qg, kg, nullptr, 0,
            lg, nullptr, nullptr,
            Tc, Tc, DH, Hc, Hc, Tc,
            (long long)TH, DH, (long long)TH, DH,
            (long long)HEADSc * TT, TT, sq, F_DIV);
        softmax_kernel<<<dim3(Ga * HEADSc * Tc), blk, 0, stream>>>(lg);
        // o = P @ V   (B = vT in [d][t] layout)
        mgemm<false><<<dim3(DH / 128, Tc / 128, Ga * HEADSc), blk, 0, stream>>>(
            lg, vg, nullptr, 0,
            og, nullptr, nullptr,
            Tc, DH, Tc, Tc, Tc, Hc,
            (long long)HEADSc * TT, TT,
            (long long)TH, (long long)DH * Tc,
            (long long)TH, DH, 1.f, 0);
        // attn_out = o @ Wo
        mgemm<true><<<dim3(Hc / 128, rows / 128, 1), blk, 0, stream>>>(
            og, nullptr, WoT, 262144LL,
            bufY + (size_t)g0 * TH, nullptr, nullptr,
            rows, Hc, Hc, Hc, 512, Hc,
            0, 0, 0, 0, 0, 0, 1.f, 0);
    }

    // ---- 3. x1 = LN(x + attn_out) in-place in bufX ----
    add_ln_kernel<<<dim3(M), blk, 0, stream>>>(bufX, bufY, ln1_g, ln1_b, bufX);

    // ---- 4. FFN, hidden chunked by Nc ----
    int nChunks = 2048 / Nc;
    for (int c = 0; c < nChunks; c++) {
        mgemm<true><<<dim3(Nc / 128, M / 128, 1), blk, 0, stream>>>(
            bufX, nullptr, W1T + (size_t)c * Nc * 512, 1048576LL,
            work, b1 + c * Nc, nullptr,
            M, Nc, Hc, Hc, 512, Nc,
            0, 0, 0, 0, 0, 0, 1.f, F_BIAS | F_RELU);
        mgemm<true><<<dim3(Hc / 128, M / 128, 1), blk, 0, stream>>>(
            work, nullptr, W2T + (size_t)c * Nc, 1048576LL,
            bufY, b2, nullptr,
            M, Hc, Nc, Nc, 2048, Hc,
            0, 0, 0, 0, 0, 0, 1.f, (c == 0) ? F_BIAS : F_ADDC);
    }

    // ---- 5. x2 = LN(x1 + f) in-place in bufX ----
    add_ln_kernel<<<dim3(M), blk, 0, stream>>>(bufX, bufY, ln2_g, ln2_b, bufX);

    // ---- 6. emissions ----
    em_kernel<<<dim3(M / 16), blk, 0, stream>>>(bufX, loc_W, loc_b, work);

    // ---- 7. viterbi ----
    viterbi_kernel<<<dim3(Bc), dim3(64), 0, stream>>>(
        work, start_trans, end_trans, trans, (int*)d_out);
}

// Round 7
// 3246.884 us; speedup vs baseline: 1.7782x; 1.3866x over previous
//
#include <hip/hip_runtime.h>
#include <math.h>

// Problem constants
constexpr int Bc = 64, Tc = 512, Hc = 512, HEADSc = 4, Lc = 16, Rc = 256, Ac = 9;
constexpr int DH = 128;

#define F_BIAS 1
#define F_PE   2
#define F_ADDC 4
#define F_RELU 8
#define F_DIV  16
#define F_QKV  32

using short8   = __attribute__((ext_vector_type(8)))  short;
using floatx16 = __attribute__((ext_vector_type(16))) float;
using ushort4v = __attribute__((ext_vector_type(4)))  unsigned short;

// Exact 3-way bf16 split by mantissa truncation: v == hi + mid + lo exactly
// (8+8+8 = 24 bits).
struct S3 { unsigned short h, m, l; };
__device__ inline S3 split3(float v)
{
    S3 r;
    unsigned u = __float_as_uint(v);
    r.h = (unsigned short)(u >> 16);
    float r1 = v - __uint_as_float(u & 0xffff0000u);
    unsigned u1 = __float_as_uint(r1);
    r.m = (unsigned short)(u1 >> 16);
    float r2 = r1 - __uint_as_float(u1 & 0xffff0000u);
    r.l = (unsigned short)(__float_as_uint(r2) >> 16);
    return r;
}

// ---------------------------------------------------------------------------
// MFMA bf16x6 GEMM. 128x128 tile, BK=32, 256 threads = 4 waves, each wave a
// 64x64 quadrant of 2x2 v_mfma_f32_32x32x16_bf16 tiles, 6 products per tile:
// hh, hm, mh, hl, lh, mm (dropped ml+lm ~2^-24, ll ~2^-32 — fp32-class).
// A: fp32 [m][k] (split in-kernel). B: either fp32 [n][k] (split in-kernel)
// or pre-split bf16 planes Bsp[3][n][k] with plane stride bPS.
// M,N multiples of 128; K multiple of 32.
// ---------------------------------------------------------------------------
template<bool BSPLIT>
__global__ __launch_bounds__(256)
void mgemm(const float* __restrict__ A, const float* __restrict__ Bf,
           const unsigned short* __restrict__ Bsp, long long bPS,
           float* __restrict__ C, const float* __restrict__ bias,
           const float* __restrict__ pe,
           int M, int N, int K, int lda, int ldb, int ldc,
           long long s1A, long long s2A, long long s1B, long long s2B,
           long long s1C, long long s2C, float divv, int flags)
{
    int z = blockIdx.z, z1 = z >> 2, z2 = z & 3;
    A += (size_t)z1 * s1A + (size_t)z2 * s2A;
    if (!BSPLIT) Bf += (size_t)z1 * s1B + (size_t)z2 * s2B;
    C += (size_t)z1 * s1C + (size_t)z2 * s2C;

    __shared__ unsigned short Ah[128][40], Am[128][40], Al[128][40];
    __shared__ unsigned short Bh[128][40], Bm[128][40], Bl[128][40];

    int bm = blockIdx.y * 128, bn = blockIdx.x * 128;
    int tid = threadIdx.x;
    int lane = tid & 63, wave = tid >> 6;
    int wr = wave >> 1, wc = wave & 1;
    int l31 = lane & 31, khalf = lane >> 5;

    floatx16 acc[2][2];
    #pragma unroll
    for (int i = 0; i < 2; i++)
        #pragma unroll
        for (int j = 0; j < 2; j++)
            #pragma unroll
            for (int e = 0; e < 16; e++) acc[i][j][e] = 0.f;

    for (int k0 = 0; k0 < K; k0 += 32) {
        // ---- stage A (fp32 -> 3 bf16 planes) ----
        #pragma unroll
        for (int it = 0; it < 4; it++) {
            int s = tid + 256 * it;
            int mm = s >> 3, kc = (s & 7) << 2;
            float4 v = *(const float4*)(A + (size_t)(bm + mm) * lda + k0 + kc);
            ushort4v h, m, l;
            S3 s0 = split3(v.x); h[0] = s0.h; m[0] = s0.m; l[0] = s0.l;
            S3 s1 = split3(v.y); h[1] = s1.h; m[1] = s1.m; l[1] = s1.l;
            S3 s2 = split3(v.z); h[2] = s2.h; m[2] = s2.m; l[2] = s2.l;
            S3 s3 = split3(v.w); h[3] = s3.h; m[3] = s3.m; l[3] = s3.l;
            *(ushort4v*)&Ah[mm][kc] = h;
            *(ushort4v*)&Am[mm][kc] = m;
            *(ushort4v*)&Al[mm][kc] = l;
        }
        // ---- stage B ----
        if (BSPLIT) {
            #pragma unroll
            for (int it = 0; it < 2; it++) {
                int s = tid + 256 * it;
                int nn = s >> 2, kc = (s & 3) << 3;
                size_t go = (size_t)(bn + nn) * ldb + k0 + kc;
                *(short8*)&Bh[nn][kc] = *(const short8*)(Bsp + go);
                *(short8*)&Bm[nn][kc] = *(const short8*)(Bsp + bPS + go);
                *(short8*)&Bl[nn][kc] = *(const short8*)(Bsp + 2 * bPS + go);
            }
        } else {
            #pragma unroll
            for (int it = 0; it < 4; it++) {
                int s = tid + 256 * it;
                int nn = s >> 3, kc = (s & 7) << 2;
                float4 v = *(const float4*)(Bf + (size_t)(bn + nn) * ldb + k0 + kc);
                ushort4v h, m, l;
                S3 s0 = split3(v.x); h[0] = s0.h; m[0] = s0.m; l[0] = s0.l;
                S3 s1 = split3(v.y); h[1] = s1.h; m[1] = s1.m; l[1] = s1.l;
                S3 s2 = split3(v.z); h[2] = s2.h; m[2] = s2.m; l[2] = s2.l;
                S3 s3 = split3(v.w); h[3] = s3.h; m[3] = s3.m; l[3] = s3.l;
                *(ushort4v*)&Bh[nn][kc] = h;
                *(ushort4v*)&Bm[nn][kc] = m;
                *(ushort4v*)&Bl[nn][kc] = l;
            }
        }
        __syncthreads();

        #pragma unroll
        for (int s = 0; s < 2; s++) {
            int ko = s * 16 + khalf * 8;
            short8 a0[2], a1[2], a2[2], b0[2], b1[2], b2[2];
            #pragma unroll
            for (int i = 0; i < 2; i++) {
                int ar = wr * 64 + i * 32 + l31;
                a0[i] = *(const short8*)&Ah[ar][ko];
                a1[i] = *(const short8*)&Am[ar][ko];
                a2[i] = *(const short8*)&Al[ar][ko];
                int br = wc * 64 + i * 32 + l31;
                b0[i] = *(const short8*)&Bh[br][ko];
                b1[i] = *(const short8*)&Bm[br][ko];
                b2[i] = *(const short8*)&Bl[br][ko];
            }
            // 6 products: hh, hm, mh, hl, lh, mm
            #pragma unroll
            for (int i = 0; i < 2; i++)
                #pragma unroll
                for (int j = 0; j < 2; j++)
                    acc[i][j] = __builtin_amdgcn_mfma_f32_32x32x16_bf16(a0[i], b0[j], acc[i][j], 0, 0, 0);
            #pragma unroll
            for (int i = 0; i < 2; i++)
                #pragma unroll
                for (int j = 0; j < 2; j++)
                    acc[i][j] = __builtin_amdgcn_mfma_f32_32x32x16_bf16(a0[i], b1[j], acc[i][j], 0, 0, 0);
            #pragma unroll
            for (int i = 0; i < 2; i++)
                #pragma unroll
                for (int j = 0; j < 2; j++)
                    acc[i][j] = __builtin_amdgcn_mfma_f32_32x32x16_bf16(a1[i], b0[j], acc[i][j], 0, 0, 0);
            #pragma unroll
            for (int i = 0; i < 2; i++)
                #pragma unroll
                for (int j = 0; j < 2; j++)
                    acc[i][j] = __builtin_amdgcn_mfma_f32_32x32x16_bf16(a0[i], b2[j], acc[i][j], 0, 0, 0);
            #pragma unroll
            for (int i = 0; i < 2; i++)
                #pragma unroll
                for (int j = 0; j < 2; j++)
                    acc[i][j] = __builtin_amdgcn_mfma_f32_32x32x16_bf16(a2[i], b0[j], acc[i][j], 0, 0, 0);
            #pragma unroll
            for (int i = 0; i < 2; i++)
                #pragma unroll
                for (int j = 0; j < 2; j++)
                    acc[i][j] = __builtin_amdgcn_mfma_f32_32x32x16_bf16(a1[i], b1[j], acc[i][j], 0, 0, 0);
        }
        __syncthreads();
    }

    // ---- epilogue: C/D layout col=lane&31, row=(reg&3)+8*(reg>>2)+4*(lane>>5)
    #pragma unroll
    for (int i = 0; i < 2; i++) {
        #pragma unroll
        for (int j = 0; j < 2; j++) {
            #pragma unroll
            for (int r = 0; r < 16; r++) {
                int m = bm + wr * 64 + i * 32 + (r & 3) + ((r >> 2) << 3) + (khalf << 2);
                int n = bn + wc * 64 + j * 32 + l31;
                float v = acc[i][j][r];
                if (flags & F_DIV)  v /= divv;
                if (flags & F_BIAS) v += bias[n];
                if (flags & F_PE)   v += pe[(size_t)(m & (Tc - 1)) * Hc + n];
                if (flags & F_QKV) {
                    long long gth = s1C;  // Ga*TH carried via s1C
                    if (n < 512) {
                        C[(size_t)m * 512 + n] = v;
                    } else if (n < 1024) {
                        C[gth + (size_t)m * 512 + (n - 512)] = v;
                    } else {
                        // V stored transposed: [b][h*128+d][t]
                        C[2 * gth + (size_t)(m >> 9) * (Tc * Hc)
                          + (size_t)(n - 1024) * Tc + (m & (Tc - 1))] = v;
                    }
                } else {
                    if (flags & F_ADDC) v += C[(size_t)m * ldc + n];
                    if (flags & F_RELU) v = fmaxf(v, 0.f);
                    C[(size_t)m * ldc + n] = v;
                }
            }
        }
    }
}

// ---------------------------------------------------------------------------
// Weight pre-split: W [K][N] fp32 -> out[3][N][K] bf16 planes (exact split).
// ---------------------------------------------------------------------------
__global__ __launch_bounds__(256)
void wsplit_kernel(const float* __restrict__ W, unsigned short* __restrict__ out,
                   int K, int N, long long PS)
{
    __shared__ float t[64][65];
    int k0 = blockIdx.x * 64, n0 = blockIdx.y * 64;
    int tid = threadIdx.x;
    int c = tid & 63, r4 = tid >> 6;
    #pragma unroll
    for (int i = 0; i < 16; i++) {
        int r = r4 * 16 + i;
        t[r][c] = W[(size_t)(k0 + r) * N + n0 + c];
    }
    __syncthreads();
    #pragma unroll
    for (int i = 0; i < 16; i++) {
        int n = r4 * 16 + i;
        S3 s = split3(t[c][n]);
        size_t o = (size_t)(n0 + n) * K + k0 + c;
        out[o] = s.h; out[PS + o] = s.m; out[2 * PS + o] = s.l;
    }
}

// ---------------------------------------------------------------------------
// Positional encoding (float64 to match numpy promotion)
// ---------------------------------------------------------------------------
__global__ void pe_kernel(float* __restrict__ pe)
{
    int idx = blockIdx.x * 256 + threadIdx.x;
    if (idx >= Tc * Hc) return;
    int t = idx >> 9, n = idx & (Hc - 1);
    int j = n >> 1;
    double div = exp(-log(10000.0) * (double)(2 * j) / (double)Hc);
    double arg = (double)t * div;
    pe[idx] = (float)((n & 1) ? cos(arg) : sin(arg));
}

// a[m,n] = dot(accl[m,:9], W[:,n]) + bias[n] + pe[t,n]
__global__ __launch_bounds__(256)
void accl_kernel(const float* __restrict__ accl, const float* __restrict__ W,
                 const float* __restrict__ bias, const float* __restrict__ pe,
                 float* __restrict__ out)
{
    int idx = blockIdx.x * 256 + threadIdx.x;
    int n = idx & (Hc - 1);
    int m = idx >> 9;
    int t = m & (Tc - 1);
    const float* arow = accl + (size_t)m * Ac;
    float s = 0.f;
    #pragma unroll
    for (int i = 0; i < Ac; i++) s += arow[i] * W[i * Hc + n];
    s += bias[n];
    s += pe[t * Hc + n];
    out[idx] = s;
}

// x = dwconv(r, cr) + dwconv(a, ca), K=3, SAME
__global__ __launch_bounds__(256)
void dwconv_kernel(const float* __restrict__ r, const float* __restrict__ a,
                   const float* __restrict__ cr, const float* __restrict__ ca,
                   float* __restrict__ x)
{
    int idx = blockIdx.x * 256 + threadIdx.x;
    int c = idx & (Hc - 1);
    int m = idx >> 9;
    int t = m & (Tc - 1);
    float vr = r[idx] * cr[Hc + c];
    if (t > 0)      vr = r[idx - Hc] * cr[c] + vr;
    if (t < Tc - 1) vr = vr + r[idx + Hc] * cr[2 * Hc + c];
    float va = a[idx] * ca[Hc + c];
    if (t > 0)      va = a[idx - Hc] * ca[c] + va;
    if (t < Tc - 1) va = va + a[idx + Hc] * ca[2 * Hc + c];
    x[idx] = vr + va;
}

// in-place row softmax over 512 columns, one block per row
__global__ __launch_bounds__(256)
void softmax_kernel(float* __restrict__ L)
{
    size_t base = (size_t)blockIdx.x * 512;
    int tid = threadIdx.x;
    float v0 = L[base + tid], v1 = L[base + tid + 256];
    __shared__ float buf[256];
    buf[tid] = fmaxf(v0, v1);
    __syncthreads();
    for (int s = 128; s > 0; s >>= 1) {
        if (tid < s) buf[tid] = fmaxf(buf[tid], buf[tid + s]);
        __syncthreads();
    }
    float mx = buf[0];
    __syncthreads();
    float e0 = expf(v0 - mx), e1 = expf(v1 - mx);
    buf[tid] = e0 + e1;
    __syncthreads();
    for (int s = 128; s > 0; s >>= 1) {
        if (tid < s) buf[tid] += buf[tid + s];
        __syncthreads();
    }
    float sum = buf[0];
    L[base + tid] = e0 / sum;
    L[base + tid + 256] = e1 / sum;
}

// out = LN(X + Y) * g + b, one block per row of 512 (out may alias X)
__global__ __launch_bounds__(256)
void add_ln_kernel(const float* __restrict__ X, const float* __restrict__ Y,
                   const float* __restrict__ g, const float* __restrict__ bta,
                   float* __restrict__ out)
{
    size_t base = (size_t)blockIdx.x * 512;
    int tid = threadIdx.x;
    float v0 = X[base + tid] + Y[base + tid];
    float v1 = X[base + tid + 256] + Y[base + tid + 256];
    __shared__ float buf[256];
    buf[tid] = v0 + v1;
    __syncthreads();
    for (int s = 128; s > 0; s >>= 1) {
        if (tid < s) buf[tid] += buf[tid + s];
        __syncthreads();
    }
    float mean = buf[0] / 512.f;
    __syncthreads();
    float d0 = v0 - mean, d1 = v1 - mean;
    buf[tid] = d0 * d0 + d1 * d1;
    __syncthreads();
    for (int s = 128; s > 0; s >>= 1) {
        if (tid < s) buf[tid] += buf[tid + s];
        __syncthreads();
    }
    float var = buf[0] / 512.f;
    float rs = 1.0f / sqrtf(var + 1e-5f);
    out[base + tid]       = d0 * rs * g[tid] + bta[tid];
    out[base + tid + 256] = d1 * rs * g[tid + 256] + bta[tid + 256];
}

// em[m, l] = dot(X[m,:512], W[:,l]) + bias[l]; W cached in LDS
__global__ __launch_bounds__(256)
void em_kernel(const float* __restrict__ X, const float* __restrict__ W,
               const float* __restrict__ bias, float* __restrict__ out)
{
    __shared__ float Wl[8192];
    int tid = threadIdx.x;
    #pragma unroll
    for (int i = 0; i < 32; i++) Wl[tid + 256 * i] = W[tid + 256 * i];
    __syncthreads();
    int r = tid >> 4, l = tid & 15;
    const float* xr = X + ((size_t)blockIdx.x * 16 + r) * Hc;
    float s = 0.f;
    #pragma unroll 8
    for (int k = 0; k < Hc; k++) s += xr[k] * Wl[k * Lc + l];
    s += bias[l];
    out[((size_t)blockIdx.x * 16 + r) * Lc + l] = s;
}

// Viterbi: one block/batch, em staged to LDS in 64-step double-buffered
// chunks (one barrier-drain per chunk instead of per step), trans column in
// registers, depth-4 first-max tree (exact numpy argmax tie semantics).
__global__ __launch_bounds__(64)
void viterbi_kernel(const float* __restrict__ em, const float* __restrict__ st,
                    const float* __restrict__ et, const float* __restrict__ trans,
                    int* __restrict__ out)
{
    int b = blockIdx.x;
    int tid = threadIdx.x;
    __shared__ float ems[2][64][Lc];           // 8 KB
    __shared__ float sc[2][Lc];
    __shared__ unsigned char hist[Tc - 1][Lc]; // ~8.2 KB
    float trcol[Lc];
    if (tid < Lc) {
        #pragma unroll
        for (int i = 0; i < Lc; i++) trcol[i] = trans[i * Lc + tid];
    }
    const float* emb = em + (size_t)b * Tc * Lc;
    {
        const float4* src = (const float4*)emb;
        float4* dst = (float4*)&ems[0][0][0];
        #pragma unroll
        for (int i = 0; i < 4; i++) dst[tid + 64 * i] = src[tid + 64 * i];
    }
    __syncthreads();
    if (tid < Lc) sc[0][tid] = st[tid] + ems[0][0][tid];
    __syncthreads();
    int cur = 0;
    for (int c = 0; c < 8; c++) {
        if (c < 7) {  // prefetch next 64-step chunk
            const float4* src = (const float4*)(emb + (size_t)(c + 1) * 64 * Lc);
            float4* dst = (float4*)&ems[(c + 1) & 1][0][0];
            #pragma unroll
            for (int i = 0; i < 4; i++) dst[tid + 64 * i] = src[tid + 64 * i];
        }
        int tt0 = (c == 0) ? 1 : 0;
        for (int tt = tt0; tt < 64; tt++) {
            int t = c * 64 + tt;
            if (tid < Lc) {
                float e = ems[c & 1][tt][tid];
                float v[Lc];
                #pragma unroll
                for (int i = 0; i < Lc; i++) v[i] = (sc[cur][i] + trcol[i]) + e;
                float bv[8]; int bi[8];
                #pragma unroll
                for (int i = 0; i < 8; i++) {
                    bool ge = v[2 * i] >= v[2 * i + 1];
                    bv[i] = ge ? v[2 * i] : v[2 * i + 1];
                    bi[i] = ge ? 2 * i : 2 * i + 1;
                }
                #pragma unroll
                for (int i = 0; i < 4; i++) {
                    bool ge = bv[2 * i] >= bv[2 * i + 1];
                    bv[i] = ge ? bv[2 * i] : bv[2 * i + 1];
                    bi[i] = ge ? bi[2 * i] : bi[2 * i + 1];
                }
                #pragma unroll
                for (int i = 0; i < 2; i++) {
                    bool ge = bv[2 * i] >= bv[2 * i + 1];
                    bv[i] = ge ? bv[2 * i] : bv[2 * i + 1];
                    bi[i] = ge ? bi[2 * i] : bi[2 * i + 1];
                }
                bool ge = bv[0] >= bv[1];
                sc[cur ^ 1][tid] = ge ? bv[0] : bv[1];
                hist[t - 1][tid] = (unsigned char)(ge ? bi[0] : bi[1]);
            }
            __syncthreads();
            cur ^= 1;
        }
    }
    if (tid == 0) {
        float best = sc[cur][0] + et[0];
        int tag = 0;
        #pragma unroll
        for (int j = 1; j < Lc; j++) {
            float v = sc[cur][j] + et[j];
            if (v > best) { best = v; tag = j; }
        }
        out[(size_t)b * Tc + (Tc - 1)] = tag;
        for (int t = Tc - 2; t >= 0; t--) {
            tag = hist[t][tag];
            out[(size_t)b * Tc + t] = tag;
        }
    }
}

__global__ void diag_kernel(int* __restrict__ out, int n, int val)
{
    int i = blockIdx.x * 256 + threadIdx.x;
    if (i < n) out[i] = val;
}

// ---------------------------------------------------------------------------
extern "C" void kernel_launch(void* const* d_in, const int* in_sizes, int n_in,
                              void* d_out, int out_size, void* d_ws, size_t ws_size,
                              hipStream_t stream)
{
    const float* rssi   = (const float*)d_in[0];
    const float* accl   = (const float*)d_in[1];
    const float* rssi_W = (const float*)d_in[2];
    const float* rssi_b = (const float*)d_in[3];
    const float* accl_W = (const float*)d_in[4];
    const float* accl_b = (const float*)d_in[5];
    const float* conv_r = (const float*)d_in[6];
    const float* conv_a = (const float*)d_in[7];
    const float* Wq     = (const float*)d_in[8];
    const float* Wk     = (const float*)d_in[9];
    const float* Wv     = (const float*)d_in[10];
    const float* Wo     = (const float*)d_in[11];
    const float* ln1_g  = (const float*)d_in[12];
    const float* ln1_b  = (const float*)d_in[13];
    const float* W1     = (const float*)d_in[14];
    const float* b1     = (const float*)d_in[15];
    const float* W2     = (const float*)d_in[16];
    const float* b2     = (const float*)d_in[17];
    const float* ln2_g  = (const float*)d_in[18];
    const float* ln2_b  = (const float*)d_in[19];
    const float* loc_W  = (const float*)d_in[20];
    const float* loc_b  = (const float*)d_in[21];
    const float* start_trans = (const float*)d_in[22];
    const float* end_trans   = (const float*)d_in[23];
    const float* trans       = (const float*)d_in[24];

    const int M = Bc * Tc;                        // 32768
    const size_t S = (size_t)M * Hc;              // 16,777,216 floats
    const size_t TH = (size_t)Tc * Hc;            // 262,144
    const long long TT = (long long)Tc * Tc;      // 262,144
    const float sq = sqrtf((float)DH);
    dim3 blk(256);

    // scratch layout (floats): bufX | bufY | wbuf(4,915,200) | pe | work
    const size_t WBUF_SH = 9830400ull;            // shorts
    const size_t WBUF_F  = WBUF_SH / 2;
    size_t total_f = ws_size / sizeof(float);
    size_t work_min = (size_t)M * 128;            // Nc=128 FFN hidden chunk
    if (total_f < 2 * S + WBUF_F + TH + work_min) {
        diag_kernel<<<dim3((out_size + 255) / 256), blk, 0, stream>>>(
            (int*)d_out, out_size, 1000000 + (int)(ws_size >> 20));
        return;
    }

    float* bufX = (float*)d_ws;
    float* bufY = bufX + S;
    unsigned short* wbuf  = (unsigned short*)(bufY + S);
    unsigned short* rssiT = wbuf;                 // [3][512][256]
    unsigned short* qkvT  = wbuf + 393216;        // [3][1536][512]
    unsigned short* WoT   = wbuf + 2752512;       // [3][512][512]
    unsigned short* W1T   = wbuf + 3538944;       // [3][2048][512]
    unsigned short* W2T   = wbuf + 6684672;       // [3][512][2048]
    float* pe_buf = (float*)(wbuf + WBUF_SH);
    float* work = pe_buf + TH;
    size_t work_n = total_f - 2 * S - WBUF_F - TH;

    int Ge = 1;
    for (int g = 64; g >= 1; g >>= 1) if ((size_t)g * TH <= work_n) { Ge = g; break; }
    int Ga = 1;
    for (int g = 64; g >= 1; g >>= 1) if (8ull * g * TH <= work_n) { Ga = g; break; }
    int Nc = 128;
    for (int n = 2048; n >= 128; n >>= 1) if ((size_t)M * n <= work_n) { Nc = n; break; }

    // ---- 0. pe + weight pre-split ----
    pe_kernel<<<dim3((Tc * Hc + 255) / 256), blk, 0, stream>>>(pe_buf);
    wsplit_kernel<<<dim3(Rc / 64, Hc / 64), blk, 0, stream>>>(rssi_W, rssiT, Rc, Hc, 131072LL);
    wsplit_kernel<<<dim3(8, 8),  blk, 0, stream>>>(Wq, qkvT,          512, 512, 786432LL);
    wsplit_kernel<<<dim3(8, 8),  blk, 0, stream>>>(Wk, qkvT + 262144, 512, 512, 786432LL);
    wsplit_kernel<<<dim3(8, 8),  blk, 0, stream>>>(Wv, qkvT + 524288, 512, 512, 786432LL);
    wsplit_kernel<<<dim3(8, 8),  blk, 0, stream>>>(Wo, WoT, 512, 512, 262144LL);
    wsplit_kernel<<<dim3(8, 32), blk, 0, stream>>>(W1, W1T, 512, 2048, 1048576LL);
    wsplit_kernel<<<dim3(32, 8), blk, 0, stream>>>(W2, W2T, 2048, 512, 1048576LL);

    // ---- 1. embed: a -> bufY (full), r -> work (grouped), x -> bufX ----
    accl_kernel<<<dim3(M * (Hc / 256)), blk, 0, stream>>>(accl, accl_W, accl_b, pe_buf, bufY);
    for (int g0 = 0; g0 < Bc; g0 += Ge) {
        int rows = Ge * Tc;
        mgemm<true><<<dim3(Hc / 128, rows / 128, 1), blk, 0, stream>>>(
            rssi + (size_t)g0 * Tc * Rc, nullptr, rssiT, 131072LL,
            work, rssi_b, pe_buf,
            rows, Hc, Rc, Rc, Rc, Hc,
            0, 0, 0, 0, 0, 0, 1.f, F_BIAS | F_PE);
        dwconv_kernel<<<dim3(rows * (Hc / 256)), blk, 0, stream>>>(
            work, bufY + (size_t)g0 * TH, conv_r, conv_a, bufX + (size_t)g0 * TH);
    }

    // ---- 2. attention per batch-group Ga ----
    for (int g0 = 0; g0 < Bc; g0 += Ga) {
        int rows = Ga * Tc;
        long long gth = (long long)Ga * TH;
        float* qg = work;                 // [rows][512]
        float* kg = work + gth;           // [rows][512]
        float* vg = work + 2 * gth;       // vT: [b][h*128+d][t]
        float* og = work + 3 * gth;       // [rows][512]
        float* lg = work + 4 * gth;       // [Ga][HEADS][T][T]
        // fused QKV (V transposed) via F_QKV, gth carried in s1C
        mgemm<true><<<dim3(1536 / 128, rows / 128, 1), blk, 0, stream>>>(
            bufX + (size_t)g0 * TH, nullptr, qkvT, 786432LL,
            qg, nullptr, nullptr,
            rows, 1536, Hc, Hc, 512, 0,
            0, 0, 0, 0, gth, 0, 1.f, F_QKV);
        // logits = q.k^T / sqrt(dh)
        mgemm<false><<<dim3(Tc / 128, Tc / 128, Ga * HEADSc), blk, 0, stream>>>(
            qg, kg, nullptr, 0,
            lg, nullptr, nullptr,
            Tc, Tc, DH, Hc, Hc, Tc,
            (long long)TH, DH, (long long)TH, DH,
            (long long)HEADSc * TT, TT, sq, F_DIV);
        softmax_kernel<<<dim3(Ga * HEADSc * Tc), blk, 0, stream>>>(lg);
        // o = P @ V   (B = vT in [d][t] layout)
        mgemm<false><<<dim3(DH / 128, Tc / 128, Ga * HEADSc), blk, 0, stream>>>(
            lg, vg, nullptr, 0,
            og, nullptr, nullptr,
            Tc, DH, Tc, Tc, Tc, Hc,
            (long long)HEADSc * TT, TT,
            (long long)TH, (long long)DH * Tc,
            (long long)TH, DH, 1.f, 0);
        // attn_out = o @ Wo
        mgemm<true><<<dim3(Hc / 128, rows / 128, 1), blk, 0, stream>>>(
            og, nullptr, WoT, 262144LL,
            bufY + (size_t)g0 * TH, nullptr, nullptr,
            rows, Hc, Hc, Hc, 512, Hc,
            0, 0, 0, 0, 0, 0, 1.f, 0);
    }

    // ---- 3. x1 = LN(x + attn_out) in-place in bufX ----
    add_ln_kernel<<<dim3(M), blk, 0, stream>>>(bufX, bufY, ln1_g, ln1_b, bufX);

    // ---- 4. FFN, hidden chunked by Nc ----
    int nChunks = 2048 / Nc;
    for (int c = 0; c < nChunks; c++) {
        mgemm<true><<<dim3(Nc / 128, M / 128, 1), blk, 0, stream>>>(
            bufX, nullptr, W1T + (size_t)c * Nc * 512, 1048576LL,
            work, b1 + c * Nc, nullptr,
            M, Nc, Hc, Hc, 512, Nc,
            0, 0, 0, 0, 0, 0, 1.f, F_BIAS | F_RELU);
        mgemm<true><<<dim3(Hc / 128, M / 128, 1), blk, 0, stream>>>(
            work, nullptr, W2T + (size_t)c * Nc, 1048576LL,
            bufY, b2, nullptr,
            M, Hc, Nc, Nc, 2048, Hc,
            0, 0, 0, 0, 0, 0, 1.f, (c == 0) ? F_BIAS : F_ADDC);
    }

    // ---- 5. x2 = LN(x1 + f) in-place in bufX ----
    add_ln_kernel<<<dim3(M), blk, 0, stream>>>(bufX, bufY, ln2_g, ln2_b, bufX);

    // ---- 6. emissions ----
    em_kernel<<<dim3(M / 16), blk, 0, stream>>>(bufX, loc_W, loc_b, work);

    // ---- 7. viterbi ----
    viterbi_kernel<<<dim3(Bc), dim3(64), 0, stream>>>(
        work, start_trans, end_trans, trans, (int*)d_out);
}